// Round 1
// baseline (321.792 us; speedup 1.0000x reference)
//
#include <hip/hip_runtime.h>
#include <float.h>

#define B_  2
#define F_  8192
#define Q_  4096
#define NC  32          // F-chunks (parallelism across CUs)
#define FC  (F_/NC)     // 256 triangles per chunk
#define PTS 256         // points per block == blockDim.x

// Branchless Ericson closest-point-on-triangle barycentrics, replicating the
// reference's jnp.select priority (first true condition wins) and
// _safe_div(n,d) = n / (d==0 ? 1 : d). Exactly one IEEE division per call.
__device__ __forceinline__ void bary_uvw(
    float ax, float ay, float az,
    float bx, float by, float bz,
    float cx, float cy, float cz,
    float px, float py, float pz,
    float& u, float& v, float& w)
{
    float abx = bx - ax, aby = by - ay, abz = bz - az;
    float acx = cx - ax, acy = cy - ay, acz = cz - az;
    float apx = px - ax, apy = py - ay, apz = pz - az;
    float d1 = abx*apx + aby*apy + abz*apz;
    float d2 = acx*apx + acy*apy + acz*apz;
    float bpx = px - bx, bpy = py - by, bpz = pz - bz;
    float d3 = abx*bpx + aby*bpy + abz*bpz;
    float d4 = acx*bpx + acy*bpy + acz*bpz;
    float qx = px - cx, qy = py - cy, qz = pz - cz;
    float d5 = abx*qx + aby*qy + abz*qz;
    float d6 = acx*qx + acy*qy + acz*qz;
    float vc = d1*d4 - d3*d2;
    float vb = d5*d2 - d1*d6;
    float va = d3*d6 - d5*d4;

    bool c1 = (d1 <= 0.f) && (d2 <= 0.f);
    bool c2 = (d3 >= 0.f) && (d4 <= d3);
    bool c3 = (vc <= 0.f) && (d1 >= 0.f) && (d3 <= 0.f);
    bool c4 = (d6 >= 0.f) && (d5 <= d6);
    bool c5 = (vb <= 0.f) && (d2 >= 0.f) && (d6 <= 0.f);
    bool c6 = (va <= 0.f) && (d4 >= d3) && (d5 >= d6);

    // first-true-wins priority chain
    bool e1 = c1;
    bool p1 = !c1;
    bool e2 = p1 && c2;
    bool p2 = p1 && !c2;
    bool e3 = p2 && c3;
    bool p3 = p2 && !c3;
    bool e4 = p3 && c4;
    bool p4 = p3 && !c4;
    bool e5 = p4 && c5;
    bool p5 = p4 && !c5;
    bool e6 = p5 && c6;
    // interior = p5 && !c6

    float d43 = d4 - d3;
    float d56 = d5 - d6;
    float n  = e3 ? d1        : (e5 ? d2        : (e6 ? d43         : 1.f));
    float dd = e3 ? (d1 - d3) : (e5 ? (d2 - d6) : (e6 ? (d43 + d56) : (va + vb + vc)));
    dd = (dd == 0.f) ? 1.f : dd;   // _safe_div
    float t = n / dd;

    float vi = vb * t;             // interior: t == inv
    float wi = vc * t;
    u = e1 ? 1.f : (e2 ? 0.f : (e3 ? 1.f - t : (e4 ? 0.f : (e5 ? 1.f - t : (e6 ? 0.f     : 1.f - vi - wi)))));
    v = e1 ? 0.f : (e2 ? 1.f : (e3 ? t       : (e4 ? 0.f : (e5 ? 0.f     : (e6 ? 1.f - t : vi)))));
    w = e1 ? 0.f : (e2 ? 0.f : (e3 ? 0.f     : (e4 ? 1.f : (e5 ? t       : (e6 ? t       : wi)))));
}

// One point per thread; block stages FC triangles into LDS; triangle loop is
// wave-uniform so every LDS read is a same-address broadcast (conflict-free).
__global__ __launch_bounds__(PTS) void scan_kernel(
    const float* __restrict__ tri, const float* __restrict__ pts,
    float* __restrict__ pd2, int* __restrict__ pix)
{
    __shared__ float4 s_tri[FC * 3];   // 12 floats per triangle (9 used), float4-aligned
    const int tid = threadIdx.x;
    const int pb = blockIdx.x, cb = blockIdx.y, bb = blockIdx.z;

    const float* g = tri + ((size_t)bb * F_ + (size_t)cb * FC) * 9;
    float* s_f = (float*)s_tri;
    for (int i = tid; i < FC * 9; i += PTS) {
        int f = i / 9;
        int r = i - f * 9;
        s_f[f * 12 + r] = g[i];
    }
    __syncthreads();

    const int q = pb * PTS + tid;
    const float* pp = pts + ((size_t)bb * Q_ + q) * 3;
    float px = pp[0], py = pp[1], pz = pp[2];

    float best = FLT_MAX;
    int besti = 0;
    #pragma unroll 2
    for (int fl = 0; fl < FC; ++fl) {
        float4 v0 = s_tri[fl * 3 + 0];
        float4 v1 = s_tri[fl * 3 + 1];
        float4 v2 = s_tri[fl * 3 + 2];
        float u, v, w;
        bary_uvw(v0.x, v0.y, v0.z,  v0.w, v1.x, v1.y,  v1.z, v1.w, v2.x,
                 px, py, pz, u, v, w);
        float cpx = u * v0.x + v * v0.w + w * v1.z;
        float cpy = u * v0.y + v * v1.x + w * v1.w;
        float cpz = u * v0.z + v * v1.y + w * v2.x;
        float dx = cpx - px, dy = cpy - py, dz = cpz - pz;
        float dist = dx * dx + dy * dy + dz * dz;
        if (dist < best) { best = dist; besti = fl; }   // strict < -> first-min wins
    }

    size_t o = ((size_t)bb * Q_ + q) * NC + cb;
    pd2[o] = best;
    pix[o] = cb * FC + besti;
}

__global__ __launch_bounds__(256) void finalize_kernel(
    const float* __restrict__ tri, const float* __restrict__ pts,
    const float* __restrict__ nrm, const float* __restrict__ cmp,
    const int* __restrict__ faces,
    const float* __restrict__ pd2, const int* __restrict__ pix,
    float* __restrict__ out)
{
    int t = blockIdx.x * 256 + threadIdx.x;
    if (t >= B_ * Q_) return;
    int bb = t / Q_;

    // reduce chunk partials; ascending chunk + strict < == jnp.argmin semantics
    size_t base = (size_t)t * NC;
    float best = FLT_MAX; int bestf = 0;
    for (int c = 0; c < NC; ++c) {
        float d = pd2[base + c];
        if (d < best) { best = d; bestf = pix[base + c]; }
    }

    const float* tg = tri + ((size_t)bb * F_ + bestf) * 9;
    const float* ng = nrm + ((size_t)bb * F_ + bestf) * 9;
    const float* cg = cmp + ((size_t)bb * F_ + bestf) * 9;
    const float* pp = pts + (size_t)t * 3;
    float px = pp[0], py = pp[1], pz = pp[2];

    float u, v, w;
    bary_uvw(tg[0], tg[1], tg[2],  tg[3], tg[4], tg[5],  tg[6], tg[7], tg[8],
             px, py, pz, u, v, w);
    u = fminf(fmaxf(u, 0.f), 1.f);
    v = fminf(fmaxf(v, 0.f), 1.f);
    w = fminf(fmaxf(w, 0.f), 1.f);

    float cpx = u * tg[0] + v * tg[3] + w * tg[6];
    float cpy = u * tg[1] + v * tg[4] + w * tg[7];
    float cpz = u * tg[2] + v * tg[5] + w * tg[8];
    float nx  = u * ng[0] + v * ng[3] + w * ng[6];
    float ny  = u * ng[1] + v * ng[4] + w * ng[7];
    float nz  = u * ng[2] + v * ng[5] + w * ng[8];
    float mx  = u * cg[0] + v * cg[3] + w * cg[6];
    float my  = u * cg[1] + v * cg[4] + w * cg[7];
    float mz  = u * cg[2] + v * cg[5] + w * cg[8];

    const size_t S3 = (size_t)B_ * Q_ * 3;
    out[(size_t)t * 3 + 0] = cpx - px;
    out[(size_t)t * 3 + 1] = cpy - py;
    out[(size_t)t * 3 + 2] = cpz - pz;
    out[S3 + (size_t)t * 3 + 0] = nx;
    out[S3 + (size_t)t * 3 + 1] = ny;
    out[S3 + (size_t)t * 3 + 2] = nz;
    out[2 * S3 + (size_t)t * 3 + 0] = mx;
    out[2 * S3 + (size_t)t * 3 + 1] = my;
    out[2 * S3 + (size_t)t * 3 + 2] = mz;

    // argmax(bcs) with first-occurrence tie-break
    int k = 0; float m = u;
    if (v > m) { m = v; k = 1; }
    if (w > m) { k = 2; }
    out[3 * S3 + t] = (float)faces[((size_t)bb * F_ + bestf) * 3 + k];
}

extern "C" void kernel_launch(void* const* d_in, const int* in_sizes, int n_in,
                              void* d_out, int out_size, void* d_ws, size_t ws_size,
                              hipStream_t stream) {
    const float* tri   = (const float*)d_in[0];
    const float* pts   = (const float*)d_in[1];
    const float* nrm   = (const float*)d_in[2];
    const float* cmp   = (const float*)d_in[3];
    const int*   faces = (const int*)d_in[4];
    float* out = (float*)d_out;

    float* pd2 = (float*)d_ws;                                  // [B*Q*NC] f32
    int*   pix = (int*)((char*)d_ws + (size_t)B_ * Q_ * NC * 4); // [B*Q*NC] i32

    dim3 g1(Q_ / PTS, NC, B_);
    scan_kernel<<<g1, PTS, 0, stream>>>(tri, pts, pd2, pix);
    finalize_kernel<<<(B_ * Q_ + 255) / 256, 256, 0, stream>>>(
        tri, pts, nrm, cmp, faces, pd2, pix, out);
}

// Round 2
// 214.804 us; speedup vs baseline: 1.4981x; 1.4981x over previous
//
#include <hip/hip_runtime.h>
#include <float.h>

#define B_  2
#define F_  8192
#define Q_  4096
#define NC  32          // F-chunks (parallelism across CUs)
#define FC  (F_/NC)     // 256 triangles per chunk
#define PTS 256         // points per block == blockDim.x

// ---------------------------------------------------------------------------
// Exact reference-order Ericson barycentrics (used only in finalize, on the
// 32 chunk-winner candidates). Replicates jnp.select first-true-wins priority
// and _safe_div(n,d) = n / (d==0 ? 1 : d). One IEEE division per call.
__device__ __forceinline__ void bary_uvw(
    float ax, float ay, float az,
    float bx, float by, float bz,
    float cx, float cy, float cz,
    float px, float py, float pz,
    float& u, float& v, float& w)
{
    float abx = bx - ax, aby = by - ay, abz = bz - az;
    float acx = cx - ax, acy = cy - ay, acz = cz - az;
    float apx = px - ax, apy = py - ay, apz = pz - az;
    float d1 = abx*apx + aby*apy + abz*apz;
    float d2 = acx*apx + acy*apy + acz*apz;
    float bpx = px - bx, bpy = py - by, bpz = pz - bz;
    float d3 = abx*bpx + aby*bpy + abz*bpz;
    float d4 = acx*bpx + acy*bpy + acz*bpz;
    float qx = px - cx, qy = py - cy, qz = pz - cz;
    float d5 = abx*qx + aby*qy + abz*qz;
    float d6 = acx*qx + acy*qy + acz*qz;
    float vc = d1*d4 - d3*d2;
    float vb = d5*d2 - d1*d6;
    float va = d3*d6 - d5*d4;

    bool c1 = (d1 <= 0.f) && (d2 <= 0.f);
    bool c2 = (d3 >= 0.f) && (d4 <= d3);
    bool c3 = (vc <= 0.f) && (d1 >= 0.f) && (d3 <= 0.f);
    bool c4 = (d6 >= 0.f) && (d5 <= d6);
    bool c5 = (vb <= 0.f) && (d2 >= 0.f) && (d6 <= 0.f);
    bool c6 = (va <= 0.f) && (d4 >= d3) && (d5 >= d6);

    bool e1 = c1;
    bool p1 = !c1;
    bool e2 = p1 && c2;
    bool p2 = p1 && !c2;
    bool e3 = p2 && c3;
    bool p3 = p2 && !c3;
    bool e4 = p3 && c4;
    bool p4 = p3 && !c4;
    bool e5 = p4 && c5;
    bool p5 = p4 && !c5;
    bool e6 = p5 && c6;

    float d43 = d4 - d3;
    float d56 = d5 - d6;
    float n  = e3 ? d1        : (e5 ? d2        : (e6 ? d43         : 1.f));
    float dd = e3 ? (d1 - d3) : (e5 ? (d2 - d6) : (e6 ? (d43 + d56) : (va + vb + vc)));
    dd = (dd == 0.f) ? 1.f : dd;   // _safe_div
    float t = n / dd;

    float vi = vb * t;
    float wi = vc * t;
    u = e1 ? 1.f : (e2 ? 0.f : (e3 ? 1.f - t : (e4 ? 0.f : (e5 ? 1.f - t : (e6 ? 0.f     : 1.f - vi - wi)))));
    v = e1 ? 0.f : (e2 ? 1.f : (e3 ? t       : (e4 ? 0.f : (e5 ? 0.f     : (e6 ? 1.f - t : vi)))));
    w = e1 ? 0.f : (e2 ? 0.f : (e3 ? 0.f     : (e4 ? 1.f : (e5 ? t       : (e6 ? t       : wi)))));
}

// ---------------------------------------------------------------------------
// Scan: cheap division-free point-triangle distance^2 using per-triangle
// precomputed data staged in LDS. Triangle loop is wave-uniform -> every LDS
// read is a broadcast (conflict-free). ~70 VALU per test.
__global__ __launch_bounds__(PTS) void scan_kernel(
    const float* __restrict__ tri, const float* __restrict__ pts,
    int* __restrict__ pix)
{
    // per-triangle: 5 x float4, stride 80 B
    // [0]: ax ay az | daa=|ab|^2
    // [1]: abx aby abz | dcc=|ac|^2
    // [2]: acx acy acz | dac=ab.ac
    // [3]: nx ny nz | rnn=1/|n|^2         (n = ab x ac)
    // [4]: rdaa rdcc rdbc | pad           (reciprocals of |ab|^2,|ac|^2,|bc|^2)
    __shared__ float4 S[FC * 5];
    const int tid = threadIdx.x;
    const int pb = blockIdx.x, cb = blockIdx.y, bb = blockIdx.z;

    // stage + derive: one triangle per thread
    {
        const float* g = tri + ((size_t)bb * F_ + (size_t)cb * FC + tid) * 9;
        float ax = g[0], ay = g[1], az = g[2];
        float bx = g[3], by = g[4], bz = g[5];
        float cx = g[6], cy = g[7], cz = g[8];
        float abx = bx - ax, aby = by - ay, abz = bz - az;
        float acx = cx - ax, acy = cy - ay, acz = cz - az;
        float bcx = cx - bx, bcy = cy - by, bcz = cz - bz;
        float daa = abx*abx + aby*aby + abz*abz;
        float dcc = acx*acx + acy*acy + acz*acz;
        float dac = abx*acx + aby*acy + abz*acz;
        float dbc = bcx*bcx + bcy*bcy + bcz*bcz;
        float nx = aby*acz - abz*acy;
        float ny = abz*acx - abx*acz;
        float nz = abx*acy - aby*acx;
        float nn = nx*nx + ny*ny + nz*nz;
        S[tid*5 + 0] = make_float4(ax, ay, az, daa);
        S[tid*5 + 1] = make_float4(abx, aby, abz, dcc);
        S[tid*5 + 2] = make_float4(acx, acy, acz, dac);
        S[tid*5 + 3] = make_float4(nx, ny, nz, 1.f / nn);
        S[tid*5 + 4] = make_float4(1.f / daa, 1.f / dcc, 1.f / dbc, 0.f);
    }
    __syncthreads();

    const int q = pb * PTS + tid;
    const float* pp = pts + ((size_t)bb * Q_ + q) * 3;
    float px = pp[0], py = pp[1], pz = pp[2];

    float best = FLT_MAX;
    int besti = 0;
    #pragma unroll 4
    for (int fl = 0; fl < FC; ++fl) {
        float4 t0 = S[fl*5 + 0];
        float4 t1 = S[fl*5 + 1];
        float4 t2 = S[fl*5 + 2];
        float4 t3 = S[fl*5 + 3];
        float4 t4 = S[fl*5 + 4];

        float apx = px - t0.x, apy = py - t0.y, apz = pz - t0.z;
        float daa = t0.w, dcc = t1.w, dac = t2.w;
        float d1  = t1.x*apx + t1.y*apy + t1.z*apz;
        float d2  = t2.x*apx + t2.y*apy + t2.z*apz;
        float apn = t3.x*apx + t3.y*apy + t3.z*apz;
        float app = apx*apx + apy*apy + apz*apz;
        float d3 = d1 - daa;
        float d4 = d2 - dac;
        float d5 = d1 - dac;
        float d6 = d2 - dcc;
        float d43 = d4 - d3;
        float d56 = d5 - d6;
        float va = d3*d6 - d5*d4;
        float vb = d5*d2 - d1*d6;
        float vc = d1*d4 - d3*d2;
        float bpp = app - 2.f*d1 + daa;   // |p-b|^2
        float cpp = app - 2.f*d2 + dcc;   // |p-c|^2

        // priority cascade (later overwrite = higher priority): c1 > ... > c6 > interior
        float base = 0.f, num = apn, rden = -t3.w;           // interior: +apn^2/nn
        bool c6 = (va <= 0.f) & (d43 >= 0.f) & (d56 >= 0.f);
        if (c6) { base = bpp; num = d43; rden = t4.z; }      // edge BC
        bool c5 = (vb <= 0.f) & (d2 >= 0.f) & (d6 <= 0.f);
        if (c5) { base = app; num = d2;  rden = t4.y; }      // edge AC
        bool c4 = (d6 >= 0.f) & (d5 <= d6);
        if (c4) { base = cpp; num = 0.f; }                   // vertex C
        bool c3 = (vc <= 0.f) & (d1 >= 0.f) & (d3 <= 0.f);
        if (c3) { base = app; num = d1;  rden = t4.x; }      // edge AB
        bool c2 = (d3 >= 0.f) & (d4 <= d3);
        if (c2) { base = bpp; num = 0.f; }                   // vertex B
        bool c1 = (d1 <= 0.f) & (d2 <= 0.f);
        if (c1) { base = app; num = 0.f; }                   // vertex A

        float dist = base - (num * num) * rden;
        if (dist < best) { best = dist; besti = fl; }        // strict < -> first-min
    }

    pix[((size_t)bb * Q_ + q) * NC + cb] = cb * FC + besti;
}

// ---------------------------------------------------------------------------
// Finalize: re-evaluate the 32 chunk winners with the EXACT reference formula
// (same code path that passed Round 1), strict-< ascending-chunk reduction,
// then gather + clipped-bary epilogue.
__global__ __launch_bounds__(256) void finalize_kernel(
    const float* __restrict__ tri, const float* __restrict__ pts,
    const float* __restrict__ nrm, const float* __restrict__ cmp,
    const int* __restrict__ faces,
    const int* __restrict__ pix,
    float* __restrict__ out)
{
    int t = blockIdx.x * 256 + threadIdx.x;
    if (t >= B_ * Q_) return;
    int bb = t / Q_;

    const float* pp = pts + (size_t)t * 3;
    float px = pp[0], py = pp[1], pz = pp[2];

    float best = FLT_MAX; int bestf = 0;
    size_t base = (size_t)t * NC;
    #pragma unroll 2
    for (int c = 0; c < NC; ++c) {
        int f = pix[base + c];
        const float* tg = tri + ((size_t)bb * F_ + f) * 9;
        float ax = tg[0], ay = tg[1], az = tg[2];
        float bx = tg[3], by = tg[4], bz = tg[5];
        float cx = tg[6], cy = tg[7], cz = tg[8];
        float u, v, w;
        bary_uvw(ax, ay, az, bx, by, bz, cx, cy, cz, px, py, pz, u, v, w);
        float cpx = u*ax + v*bx + w*cx;
        float cpy = u*ay + v*by + w*cy;
        float cpz = u*az + v*bz + w*cz;
        float dx = cpx - px, dy = cpy - py, dz = cpz - pz;
        float d2 = dx*dx + dy*dy + dz*dz;
        if (d2 < best) { best = d2; bestf = f; }   // ascending chunk + strict <
    }

    const float* tg = tri + ((size_t)bb * F_ + bestf) * 9;
    const float* ng = nrm + ((size_t)bb * F_ + bestf) * 9;
    const float* cg = cmp + ((size_t)bb * F_ + bestf) * 9;

    float u, v, w;
    bary_uvw(tg[0], tg[1], tg[2],  tg[3], tg[4], tg[5],  tg[6], tg[7], tg[8],
             px, py, pz, u, v, w);
    u = fminf(fmaxf(u, 0.f), 1.f);
    v = fminf(fmaxf(v, 0.f), 1.f);
    w = fminf(fmaxf(w, 0.f), 1.f);

    float cpx = u * tg[0] + v * tg[3] + w * tg[6];
    float cpy = u * tg[1] + v * tg[4] + w * tg[7];
    float cpz = u * tg[2] + v * tg[5] + w * tg[8];
    float nx  = u * ng[0] + v * ng[3] + w * ng[6];
    float ny  = u * ng[1] + v * ng[4] + w * ng[7];
    float nz  = u * ng[2] + v * ng[5] + w * ng[8];
    float mx  = u * cg[0] + v * cg[3] + w * cg[6];
    float my  = u * cg[1] + v * cg[4] + w * cg[7];
    float mz  = u * cg[2] + v * cg[5] + w * cg[8];

    const size_t S3 = (size_t)B_ * Q_ * 3;
    out[(size_t)t * 3 + 0] = cpx - px;
    out[(size_t)t * 3 + 1] = cpy - py;
    out[(size_t)t * 3 + 2] = cpz - pz;
    out[S3 + (size_t)t * 3 + 0] = nx;
    out[S3 + (size_t)t * 3 + 1] = ny;
    out[S3 + (size_t)t * 3 + 2] = nz;
    out[2 * S3 + (size_t)t * 3 + 0] = mx;
    out[2 * S3 + (size_t)t * 3 + 1] = my;
    out[2 * S3 + (size_t)t * 3 + 2] = mz;

    int k = 0; float m = u;
    if (v > m) { m = v; k = 1; }
    if (w > m) { k = 2; }
    out[3 * S3 + t] = (float)faces[((size_t)bb * F_ + bestf) * 3 + k];
}

extern "C" void kernel_launch(void* const* d_in, const int* in_sizes, int n_in,
                              void* d_out, int out_size, void* d_ws, size_t ws_size,
                              hipStream_t stream) {
    const float* tri   = (const float*)d_in[0];
    const float* pts   = (const float*)d_in[1];
    const float* nrm   = (const float*)d_in[2];
    const float* cmp   = (const float*)d_in[3];
    const int*   faces = (const int*)d_in[4];
    float* out = (float*)d_out;

    int* pix = (int*)d_ws;   // [B*Q*NC] i32, fully written by scan before finalize

    dim3 g1(Q_ / PTS, NC, B_);
    scan_kernel<<<g1, PTS, 0, stream>>>(tri, pts, pix);
    finalize_kernel<<<(B_ * Q_ + 255) / 256, 256, 0, stream>>>(
        tri, pts, nrm, cmp, faces, pix, out);
}

// Round 4
// 152.579 us; speedup vs baseline: 2.1090x; 1.4078x over previous
//
#include <hip/hip_runtime.h>
#include <float.h>

#define B_   2
#define F_   8192
#define Q_   4096
#define NC   64          // F-chunks == lanes per point in finalize
#define FC   (F_/NC)     // 128 triangles per chunk
#define PTS  256         // threads per scan block
#define PPT  2           // points per thread in scan (packed fp32)

typedef float f2 __attribute__((ext_vector_type(2)));

__device__ __forceinline__ f2 clamp01(f2 x) {
    f2 z = {0.f, 0.f}, o = {1.f, 1.f};
    return __builtin_elementwise_min(__builtin_elementwise_max(x, z), o);
}

// ---------------------------------------------------------------------------
// Exact reference-order Ericson barycentrics (finalize only). FMA contraction
// OFF so every op rounds exactly like the numpy reference; op order matches
// the reference term-for-term. Replicates jnp.select first-true-wins priority
// and _safe_div(n,d) = n / (d==0 ? 1 : d).
__device__ __forceinline__ void bary_uvw(
    float ax, float ay, float az,
    float bx, float by, float bz,
    float cx, float cy, float cz,
    float px, float py, float pz,
    float& u, float& v, float& w)
{
#pragma clang fp contract(off)
    float abx = bx - ax, aby = by - ay, abz = bz - az;
    float acx = cx - ax, acy = cy - ay, acz = cz - az;
    float apx = px - ax, apy = py - ay, apz = pz - az;
    float d1 = abx*apx + aby*apy + abz*apz;
    float d2 = acx*apx + acy*apy + acz*apz;
    float bpx = px - bx, bpy = py - by, bpz = pz - bz;
    float d3 = abx*bpx + aby*bpy + abz*bpz;
    float d4 = acx*bpx + acy*bpy + acz*bpz;
    float qx = px - cx, qy = py - cy, qz = pz - cz;
    float d5 = abx*qx + aby*qy + abz*qz;
    float d6 = acx*qx + acy*qy + acz*qz;
    float vc = d1*d4 - d3*d2;
    float vb = d5*d2 - d1*d6;
    float va = d3*d6 - d5*d4;

    bool c1 = (d1 <= 0.f) && (d2 <= 0.f);
    bool c2 = (d3 >= 0.f) && (d4 <= d3);
    bool c3 = (vc <= 0.f) && (d1 >= 0.f) && (d3 <= 0.f);
    bool c4 = (d6 >= 0.f) && (d5 <= d6);
    bool c5 = (vb <= 0.f) && (d2 >= 0.f) && (d6 <= 0.f);
    bool c6 = (va <= 0.f) && (d4 >= d3) && (d5 >= d6);

    bool e1 = c1;
    bool p1 = !c1;
    bool e2 = p1 && c2;
    bool p2 = p1 && !c2;
    bool e3 = p2 && c3;
    bool p3 = p2 && !c3;
    bool e4 = p3 && c4;
    bool p4 = p3 && !c4;
    bool e5 = p4 && c5;
    bool p5 = p4 && !c5;
    bool e6 = p5 && c6;

    float d43 = d4 - d3;
    float d56 = d5 - d6;
    float n  = e3 ? d1        : (e5 ? d2        : (e6 ? d43         : 1.f));
    float dd = e3 ? (d1 - d3) : (e5 ? (d2 - d6) : (e6 ? (d43 + d56) : (va + vb + vc)));
    dd = (dd == 0.f) ? 1.f : dd;   // _safe_div
    float t = n / dd;

    float vi = vb * t;
    float wi = vc * t;
    u = e1 ? 1.f : (e2 ? 0.f : (e3 ? 1.f - t : (e4 ? 0.f : (e5 ? 1.f - t : (e6 ? 0.f     : 1.f - vi - wi)))));
    v = e1 ? 0.f : (e2 ? 1.f : (e3 ? t       : (e4 ? 0.f : (e5 ? 0.f     : (e6 ? 1.f - t : vi)))));
    w = e1 ? 0.f : (e2 ? 0.f : (e3 ? 0.f     : (e4 ? 1.f : (e5 ? t       : (e6 ? t       : wi)))));
}

// ---------------------------------------------------------------------------
// Scan: 2 points per thread, packed fp32. Distance = inside ? plane-dist^2
// (Gram identity) : min3(edge-segment dist^2). Reports TOP-2 faces per chunk
// (packed 16+16 bits) so a within-chunk near-tie flip cannot drop the true
// winner. Triangle record: 4 x float4 in LDS, wave-uniform broadcast reads.
__global__ __launch_bounds__(PTS) void scan_kernel(
    const float* __restrict__ tri, const float* __restrict__ pts,
    int* __restrict__ pix)
{
    // [0]: ax ay az | daa=|ab|^2
    // [1]: abx aby abz | dcc=|ac|^2
    // [2]: acx acy acz | dac=ab.ac
    // [3]: rdaa rdcc rdbc | rnn
    __shared__ float4 S[FC * 4];
    const int tid = threadIdx.x;
    const int pb = blockIdx.x, cb = blockIdx.y, bb = blockIdx.z;

    {
        const int tr = tid & (FC - 1);
        const int hf = tid >> 7;
        const float* g = tri + ((size_t)bb * F_ + (size_t)cb * FC + tr) * 9;
        float ax = g[0], ay = g[1], az = g[2];
        float bx = g[3], by = g[4], bz = g[5];
        float cx = g[6], cy = g[7], cz = g[8];
        float abx = bx - ax, aby = by - ay, abz = bz - az;
        float acx = cx - ax, acy = cy - ay, acz = cz - az;
        float daa = abx*abx + aby*aby + abz*abz;
        float dcc = acx*acx + acy*acy + acz*acz;
        float dac = abx*acx + aby*acy + abz*acz;
        float dbc = daa + dcc - 2.f*dac;
        float nn  = daa*dcc - dac*dac;
        if (hf == 0) {
            S[tr*4 + 0] = make_float4(ax, ay, az, daa);
            S[tr*4 + 1] = make_float4(abx, aby, abz, dcc);
        } else {
            S[tr*4 + 2] = make_float4(acx, acy, acz, dac);
            S[tr*4 + 3] = make_float4(1.f/daa, 1.f/dcc, 1.f/dbc, 1.f/nn);
        }
    }
    __syncthreads();

    const int q0 = pb * (PTS * PPT) + tid * PPT;
    const float* p0 = pts + ((size_t)bb * Q_ + q0) * 3;
    f2 px = {p0[0], p0[3]};
    f2 py = {p0[1], p0[4]};
    f2 pz = {p0[2], p0[5]};

    float bA0 = FLT_MAX, bA1 = FLT_MAX;   // point0: best, second-best
    float bB0 = FLT_MAX, bB1 = FLT_MAX;   // point1
    int iA0 = 0, iA1 = 0, iB0 = 0, iB1 = 0;
    #pragma unroll 2
    for (int fl = 0; fl < FC; ++fl) {
        float4 c0 = S[fl*4 + 0];
        float4 c1 = S[fl*4 + 1];
        float4 c2 = S[fl*4 + 2];
        float4 c3 = S[fl*4 + 3];
        float daa = c0.w, dcc = c1.w, dac = c2.w;
        float dbc = daa + dcc - 2.f*dac;

        f2 apx = px - c0.x, apy = py - c0.y, apz = pz - c0.z;
        f2 d1  = c1.x*apx + c1.y*apy + c1.z*apz;
        f2 d2  = c2.x*apx + c2.y*apy + c2.z*apz;
        f2 app = apx*apx + apy*apy + apz*apz;
        f2 d3 = d1 - daa, d4 = d2 - dac, d5 = d1 - dac, d6 = d2 - dcc;
        f2 d43 = d4 - d3;
        f2 va = d3*d6 - d5*d4;
        f2 vb = d5*d2 - d1*d6;
        f2 vc = d1*d4 - d3*d2;

        // interior: app - [d1 d2] G^-1 [d1 d2]^T (Gram; no normal vector)
        f2 t1 = d1*dcc - d2*dac;
        f2 t2 = d2*daa - d1*dac;
        f2 sg = d1*t1 + d2*t2;
        f2 dint = app - sg*c3.w;

        f2 td1 = d1 + d1;
        f2 tab = clamp01(d1 * c3.x);
        f2 eab = app - tab*(td1 - tab*daa);
        f2 tac = clamp01(d2 * c3.y);
        f2 eac = app - tac*(d2 + d2 - tac*dcc);
        f2 bpp = app - td1 + daa;
        f2 sbc = clamp01(d43 * c3.z);
        f2 ebc = bpp - sbc*(d43 + d43 - sbc*dbc);

        f2 emin = __builtin_elementwise_min(__builtin_elementwise_min(eab, eac), ebc);

        bool in0 = (va.x >= 0.f) && (vb.x >= 0.f) && (vc.x >= 0.f);
        bool in1 = (va.y >= 0.f) && (vb.y >= 0.f) && (vc.y >= 0.f);
        float dA = in0 ? dint.x : emin.x;
        float dB = in1 ? dint.y : emin.y;

        // top-2 tracking, first-occurrence on ties (strict <)
        bool a1 = dA < bA0, a2 = dA < bA1;
        bA1 = a1 ? bA0 : (a2 ? dA : bA1);
        iA1 = a1 ? iA0 : (a2 ? fl : iA1);
        bA0 = a1 ? dA : bA0;
        iA0 = a1 ? fl : iA0;
        bool b1 = dB < bB0, b2 = dB < bB1;
        bB1 = b1 ? bB0 : (b2 ? dB : bB1);
        iB1 = b1 ? iB0 : (b2 ? fl : iB1);
        bB0 = b1 ? dB : bB0;
        iB0 = b1 ? fl : iB0;
    }

    const int fb = cb * FC;
    size_t o = ((size_t)bb * Q_ + q0) * NC + cb;
    pix[o]      = (fb + iA0) | ((fb + iA1) << 16);
    pix[o + NC] = (fb + iB0) | ((fb + iB1) << 16);
}

// ---------------------------------------------------------------------------
// Finalize: one WAVE per point, one lane per chunk (2 candidates each, 128
// total). Candidates evaluated with the exact np-order formula (contract off
// -> bitwise-identical d^2), lex-(d, face) reduce == jnp.argmin first
// occurrence. Lane 0 does the epilogue, also contract-off (bitwise outputs).
__global__ __launch_bounds__(256) void finalize_kernel(
    const float* __restrict__ tri, const float* __restrict__ pts,
    const float* __restrict__ nrm, const float* __restrict__ cmp,
    const int* __restrict__ faces,
    const int* __restrict__ pix,
    float* __restrict__ out)
{
#pragma clang fp contract(off)
    const int lane = threadIdx.x & 63;
    const int t = blockIdx.x * 4 + (threadIdx.x >> 6);
    const int bb = t / Q_;

    const float* pp = pts + (size_t)t * 3;
    float px = pp[0], py = pp[1], pz = pp[2];

    int pk = pix[(size_t)t * NC + lane];
    int fc0 = pk & 0xFFFF;
    int fc1 = (pk >> 16) & 0xFFFF;

    float dbest; int fbest;
    {
        float dcand[2]; int fcand[2] = {fc0, fc1};
        #pragma unroll
        for (int j = 0; j < 2; ++j) {
            const float* tg = tri + ((size_t)bb * F_ + fcand[j]) * 9;
            float ax = tg[0], ay = tg[1], az = tg[2];
            float bx = tg[3], by = tg[4], bz = tg[5];
            float cx = tg[6], cy = tg[7], cz = tg[8];
            float u, v, w;
            bary_uvw(ax, ay, az, bx, by, bz, cx, cy, cz, px, py, pz, u, v, w);
            float cpx = u*ax + v*bx + w*cx;
            float cpy = u*ay + v*by + w*cy;
            float cpz = u*az + v*bz + w*cz;
            float dx = cpx - px, dy = cpy - py, dz = cpz - pz;
            dcand[j] = dx*dx + dy*dy + dz*dz;
        }
        // within-lane lex-min (d, face)
        if (dcand[1] < dcand[0] || (dcand[1] == dcand[0] && fcand[1] < fcand[0])) {
            dbest = dcand[1]; fbest = fcand[1];
        } else {
            dbest = dcand[0]; fbest = fcand[0];
        }
        // wave lex-min (d, face) — face order == global first-occurrence
        for (int off = 32; off > 0; off >>= 1) {
            float od = __shfl_down(dbest, off);
            int   of = __shfl_down(fbest, off);
            if (od < dbest || (od == dbest && of < fbest)) { dbest = od; fbest = of; }
        }
        fbest = __shfl(fbest, 0);
    }
    if (lane != 0) return;

    const int bestf = fbest;
    const float* tg = tri + ((size_t)bb * F_ + bestf) * 9;
    const float* ng = nrm + ((size_t)bb * F_ + bestf) * 9;
    const float* cg = cmp + ((size_t)bb * F_ + bestf) * 9;

    float u, v, w;
    bary_uvw(tg[0], tg[1], tg[2],  tg[3], tg[4], tg[5],  tg[6], tg[7], tg[8],
             px, py, pz, u, v, w);
    u = fminf(fmaxf(u, 0.f), 1.f);
    v = fminf(fmaxf(v, 0.f), 1.f);
    w = fminf(fmaxf(w, 0.f), 1.f);

    float cpx = u * tg[0] + v * tg[3] + w * tg[6];
    float cpy = u * tg[1] + v * tg[4] + w * tg[7];
    float cpz = u * tg[2] + v * tg[5] + w * tg[8];
    float nx  = u * ng[0] + v * ng[3] + w * ng[6];
    float ny  = u * ng[1] + v * ng[4] + w * ng[7];
    float nz  = u * ng[2] + v * ng[5] + w * ng[8];
    float mx  = u * cg[0] + v * cg[3] + w * cg[6];
    float my  = u * cg[1] + v * cg[4] + w * cg[7];
    float mz  = u * cg[2] + v * cg[5] + w * cg[8];

    const size_t S3 = (size_t)B_ * Q_ * 3;
    out[(size_t)t * 3 + 0] = cpx - px;
    out[(size_t)t * 3 + 1] = cpy - py;
    out[(size_t)t * 3 + 2] = cpz - pz;
    out[S3 + (size_t)t * 3 + 0] = nx;
    out[S3 + (size_t)t * 3 + 1] = ny;
    out[S3 + (size_t)t * 3 + 2] = nz;
    out[2 * S3 + (size_t)t * 3 + 0] = mx;
    out[2 * S3 + (size_t)t * 3 + 1] = my;
    out[2 * S3 + (size_t)t * 3 + 2] = mz;

    int k = 0; float m = u;
    if (v > m) { m = v; k = 1; }
    if (w > m) { k = 2; }
    out[3 * S3 + t] = (float)faces[((size_t)bb * F_ + bestf) * 3 + k];
}

extern "C" void kernel_launch(void* const* d_in, const int* in_sizes, int n_in,
                              void* d_out, int out_size, void* d_ws, size_t ws_size,
                              hipStream_t stream) {
    const float* tri   = (const float*)d_in[0];
    const float* pts   = (const float*)d_in[1];
    const float* nrm   = (const float*)d_in[2];
    const float* cmp   = (const float*)d_in[3];
    const int*   faces = (const int*)d_in[4];
    float* out = (float*)d_out;

    int* pix = (int*)d_ws;   // [B*Q*NC] packed top-2 faces; fully written by scan

    dim3 g1(Q_ / (PTS * PPT), NC, B_);
    scan_kernel<<<g1, PTS, 0, stream>>>(tri, pts, pix);
    finalize_kernel<<<(B_ * Q_) / 4, 256, 0, stream>>>(
        tri, pts, nrm, cmp, faces, pix, out);
}